// Round 7
// baseline (355.744 us; speedup 1.0000x reference)
//
#include <hip/hip_runtime.h>
#include <hip/hip_bf16.h>

// NTM cell forward: T=512, B=32, D=1024, N=128. All I/O f32.
// R16 == R15 resubmitted (previous round hit an infra failure, no data).
// R15: defeat prefetch-sinking in the scan. R14's scan reports
// VGPR_Count=32 — too small for the 55+ reg live set of a real depth-2
// prefetch -> the compiler sank all slot loads to their uses (legal,
// minimizes liveness), so every t stalls on L2/L3 latency at first use.
// Fix: asm keep-alive pins force each slot's loaded values into VGPRs at
// the END of the body that issued them (~130cy after issue, ~1.5 bodies
// before use). Everything else identical to R14 (passed, absmax 8.0).

typedef __attribute__((ext_vector_type(8))) short bf16x8;
typedef __attribute__((ext_vector_type(4))) float f32x4;
typedef __attribute__((ext_vector_type(2))) float f32x2;
typedef __attribute__((ext_vector_type(4))) unsigned short u16x4;
typedef __attribute__((ext_vector_type(8))) unsigned short u16x8;

static constexpr int T_STEPS = 512;
static constexpr int BATCH   = 32;
static constexpr int DDIM    = 1024;
static constexpr int NDIM    = 128;
static constexpr int LDC     = 5 * NDIM;         // 640
static constexpr int MROWS   = T_STEPS * BATCH;  // 16384
static constexpr int OUT_N   = T_STEPS * BATCH * NDIM;  // 2,097,152

static constexpr size_t C_BYTES = (size_t)MROWS * LDC * 4;  // 41,943,040

// round-to-nearest-even f32 -> bf16
__device__ __forceinline__ unsigned short rne_bf16(float v) {
    unsigned u = __builtin_bit_cast(unsigned, v);
    u += 0x7FFFu + ((u >> 16) & 1u);
    return (unsigned short)(u >> 16);
}

// ---------------- Phase 0: W f32 -> frag-swizzled bf16 ----------------
__global__ __launch_bounds__(256) void wconv_kernel(
    const float* __restrict__ w0, const float* __restrict__ w1,
    const float* __restrict__ w2, const float* __restrict__ w3,
    const float* __restrict__ w4,
    unsigned short* __restrict__ W2)
{
    const int idx = blockIdx.x * 256 + threadIdx.x;   // f32x4 index, 163840 total
    const size_t e = (size_t)idx * 4;
    const int bn = (int)(e >> 17);                    // 131,072 elems per weight
    const int r  = (int)(e & 131071);
    const int n  = r >> 10;
    const int k  = r & 1023;

    const float* wp = w0;
    if (bn == 1) wp = w1;
    else if (bn == 2) wp = w2;
    else if (bn == 3) wp = w3;
    else if (bn == 4) wp = w4;

    f32x4 v = *(const f32x4*)(wp + r);
    u16x4 h;
#pragma unroll
    for (int j = 0; j < 4; ++j) h[j] = rne_bf16(v[j]);

    const int kk   = k >> 5;
    const int quad = (k >> 3) & 3;
    const size_t off = ((((size_t)(bn * 32 + kk) * 128 + n) * 4 + quad) * 8) + (k & 7);
    *(u16x4*)(W2 + off) = h;
}

// ---------------- Phase 1: A-resident GEMM, bn-pass structure ----------------
template<int BN0, int NB>
__device__ __forceinline__ void gemm_pass(
    const unsigned short (&lds)[64 * 1024],
    const unsigned short* __restrict__ bp,
    float* __restrict__ C,
    int m0, int wave, int quad, int l16, int aswz)
{
    auto LDA = [&](int mi, int kk) -> bf16x8 {
        const int byteo = (mi * 16 + l16) * 2048 + ((kk * 64 + quad * 16) ^ aswz);
        return *(const bf16x8*)((const char*)lds + byteo);
    };

    f32x4 acc[NB][4];
#pragma unroll
    for (int q = 0; q < NB; ++q)
#pragma unroll
        for (int mi = 0; mi < 4; ++mi) acc[q][mi] = (f32x4)(0.0f);

    const unsigned short* bpp[NB];
#pragma unroll
    for (int q = 0; q < NB; ++q) bpp[q] = bp + (size_t)(BN0 + q) * 131072;

    bf16x8 aC[4], bC[NB], aN[4], bN[NB];
#pragma unroll
    for (int mi = 0; mi < 4; ++mi) aC[mi] = LDA(mi, 0);
#pragma unroll
    for (int q = 0; q < NB; ++q) bC[q] = *(const bf16x8*)bpp[q];

    for (int kk = 0; kk < 32; kk += 2) {
        // prefetch kk+1
#pragma unroll
        for (int mi = 0; mi < 4; ++mi) aN[mi] = LDA(mi, kk + 1);
#pragma unroll
        for (int q = 0; q < NB; ++q)
            bN[q] = *(const bf16x8*)(bpp[q] + (size_t)(kk + 1) * 4096);
        // compute kk
#pragma unroll
        for (int q = 0; q < NB; ++q)
#pragma unroll
            for (int mi = 0; mi < 4; ++mi)
                acc[q][mi] = __builtin_amdgcn_mfma_f32_16x16x32_bf16(
                    aC[mi], bC[q], acc[q][mi], 0, 0, 0);
        // prefetch kk+2
        if (kk < 30) {
#pragma unroll
            for (int mi = 0; mi < 4; ++mi) aC[mi] = LDA(mi, kk + 2);
#pragma unroll
            for (int q = 0; q < NB; ++q)
                bC[q] = *(const bf16x8*)(bpp[q] + (size_t)(kk + 2) * 4096);
        }
        // compute kk+1
#pragma unroll
        for (int q = 0; q < NB; ++q)
#pragma unroll
            for (int mi = 0; mi < 4; ++mi)
                acc[q][mi] = __builtin_amdgcn_mfma_f32_16x16x32_bf16(
                    aN[mi], bN[q], acc[q][mi], 0, 0, 0);
    }

    // per-pass epilogue (overlaps next pass's loads)
#pragma unroll
    for (int q = 0; q < NB; ++q)
#pragma unroll
        for (int mi = 0; mi < 4; ++mi) {
            const int rw = m0 + mi * 16 + quad * 4;
            const int cl = (BN0 + q) * 128 + wave * 16 + l16;
#pragma unroll
            for (int r = 0; r < 4; ++r)
                C[(size_t)(rw + r) * LDC + cl] = acc[q][mi][r];
        }
}

// 256 blocks, 512 threads (8 waves), 1 block/CU (128 KiB LDS).
__global__ __launch_bounds__(512, 2) void gemm5_kernel(
    const float* __restrict__ x,
    const unsigned short* __restrict__ W2,
    float* __restrict__ C)
{
    __shared__ unsigned short lds[64 * 1024];  // 131,072 B

    const int m0   = blockIdx.x * 64;
    const int tid  = threadIdx.x;
    const int wave = tid >> 6, lane = tid & 63;
    const int quad = lane >> 4, l16 = lane & 15;

    // ---- stage: coalesced 32 B/thread/iter, swizzled 16 B LDS writes ----
    {
        const int k8 = tid & 127;       // 8-elem k-group 0..127
        const int rb = tid >> 7;        // 0..3
#pragma unroll 4
        for (int it = 0; it < 16; ++it) {
            const int row = it * 4 + rb;
            const float* src = x + (size_t)(m0 + row) * DDIM + k8 * 8;
            f32x4 v0 = *(const f32x4*)src;
            f32x4 v1 = *(const f32x4*)(src + 4);
            u16x8 h;
            h[0] = rne_bf16(v0[0]); h[1] = rne_bf16(v0[1]);
            h[2] = rne_bf16(v0[2]); h[3] = rne_bf16(v0[3]);
            h[4] = rne_bf16(v1[0]); h[5] = rne_bf16(v1[1]);
            h[6] = rne_bf16(v1[2]); h[7] = rne_bf16(v1[3]);
            const int byteo = row * 2048 + ((k8 * 16) ^ ((row & 7) << 4));
            *(u16x8*)((char*)lds + byteo) = h;
        }
    }
    __syncthreads();

    const int aswz = (l16 & 7) << 4;
    const unsigned short* bp = W2 + ((size_t)((wave * 16 + l16) * 4 + quad)) * 8;

    gemm_pass<0, 2>(lds, bp, C, m0, wave, quad, l16, aswz);
    gemm_pass<2, 2>(lds, bp, C, m0, wave, quad, l16, aswz);
    gemm_pass<4, 1>(lds, bp, C, m0, wave, quad, l16, aswz);
}

// ---------------- knorm prep ----------------
__global__ __launch_bounds__(256) void knorm_kernel(float* __restrict__ C)
{
    const int r    = blockIdx.x * 4 + (threadIdx.x >> 6);
    const int lane = threadIdx.x & 63;
    float* base = C + (size_t)r * LDC;

    f32x2 k2 = *(const f32x2*)(base + lane * 2);
    f32x2 v2 = *(const f32x2*)(base + NDIM + lane * 2);
    f32x2 w2 = *(const f32x2*)(base + 4 * NDIM + lane * 2);

    float ss = k2.x * k2.x + k2.y * k2.y;
#pragma unroll
    for (int off = 32; off >= 1; off >>= 1) ss += __shfl_xor(ss, off, 64);
    float inv = __builtin_amdgcn_rcpf(sqrtf(ss) + 1e-6f);

    f32x2 kn = {k2.x * inv, k2.y * inv};
    f32x2 wv = {v2.x * w2.x, v2.y * w2.y};
    *(f32x2*)(base + lane * 2) = kn;
    *(f32x2*)(base + NDIM + lane * 2) = wv;
}

// ---------------- recurrent scan ----------------
__device__ __forceinline__ float tanh_fast(float xx) {
    float ex = __builtin_amdgcn_exp2f(xx * 2.8853900817779268f);  // e^(2x)
    float r  = __builtin_amdgcn_rcpf(ex + 1.0f);
    return fmaf(-2.0f, r, 1.0f);
}

template <int CTRL, int RMASK>
__device__ __forceinline__ float dpp_add(float x) {
    int yi = __builtin_amdgcn_update_dpp(
        0, __builtin_bit_cast(int, x), CTRL, RMASK, 0xF, true);
    return x + __builtin_bit_cast(float, yi);
}

// Sum across each 32-lane group; valid in lanes 16..31 / 48..63.
__device__ __forceinline__ float dpp_reduce32(float x) {
    x = dpp_add<0xB1,  0xF>(x);  // + lane^1
    x = dpp_add<0x4E,  0xF>(x);  // + lane^2
    x = dpp_add<0x141, 0xF>(x);  // row_half_mirror: + lane^4
    x = dpp_add<0x140, 0xF>(x);  // row_mirror: + lane^8
    x = dpp_add<0x142, 0xA>(x);  // row_bcast15: rows 1,3 += row 0,2 sum
    return x;
}

// Keep-alive pin: forces the slot's loaded values to be resident in VGPRs
// at this program point (defeats load-sinking; the vmcnt wait lands here,
// ~1 body after issue and ~1 body before use, covered by compute).
__device__ __forceinline__ void keep_slot(f32x4& k4, f32x4& q4, float& e, float& wv) {
    float k0 = k4[0], k1 = k4[1], k2 = k4[2], k3 = k4[3];
    float q0 = q4[0], q1 = q4[1], q2 = q4[2], q3 = q4[3];
    asm volatile("" : "+v"(k0), "+v"(k1), "+v"(k2), "+v"(k3),
                      "+v"(q0), "+v"(q1), "+v"(q2), "+v"(q3),
                      "+v"(e), "+v"(wv));
    k4[0] = k0; k4[1] = k1; k4[2] = k2; k4[3] = k3;
    q4[0] = q0; q4[1] = q1; q4[2] = q2; q4[3] = q3;
}

// Grid 512 x 256; 32-lane group per S-row, 4 f32/lane, 2 rows/wave.
__global__ __launch_bounds__(256, 2) void ntm_scan_kernel(
    const float* __restrict__ C, const float* __restrict__ S0,
    float* __restrict__ out)
{
    const int L    = blockIdx.x;            // 0..511
    const int b    = (L & 7) + 8 * ((L >> 3) & 3);
    const int row  = (L >> 5) * 8 + (threadIdx.x >> 5);
    const int g    = threadIdx.x & 31;
    const int col0 = g * 4;

    f32x4 S = *(const f32x4*)(S0 + ((size_t)b * NDIM + row) * NDIM + col0);

    const size_t STRIDE = (size_t)BATCH * LDC;
    const float* pb = C + (size_t)b * LDC;

    f32x4 kS[4], qS[4];
    float eS[4], wvS[4];

#pragma unroll
    for (int s = 0; s < 2; ++s) {
        const float* p = pb + (size_t)s * STRIDE;
        kS[s]  = *(const f32x4*)(p + col0);
        qS[s]  = *(const f32x4*)(p + 2 * NDIM + col0);
        eS[s]  = p[3 * NDIM + row];
        wvS[s] = p[NDIM + row];
    }

    float* opc = out + (size_t)b * NDIM + row;   // store cursor
    const float* pc = pb + 2 * STRIDE;           // prefetch cursor (t+2)

    for (int ti = 0; ti < 127; ++ti) {
#pragma unroll
        for (int j = 0; j < 4; ++j) {
            const int ps = (j + 2) & 3;
            kS[ps]  = *(const f32x4*)(pc + col0);
            qS[ps]  = *(const f32x4*)(pc + 2 * NDIM + col0);
            eS[ps]  = pc[3 * NDIM + row];
            wvS[ps] = pc[NDIM + row];
            pc += STRIDE;

            float dot = 0.0f;
#pragma unroll
            for (int u = 0; u < 4; ++u) {
                float t0  = fmaf(-eS[j], S[u], wvS[j]);
                float pre = fmaf(kS[j][u], t0, S[u]);
                S[u] = tanh_fast(pre);
                dot = fmaf(S[u], qS[j][u], dot);
            }
            dot = dpp_reduce32(dot);

            if ((threadIdx.x & 31) == 31)
                *opc = dot;  // raw; silu in epilogue
            opc += BATCH * NDIM;

            // pin this body's prefetch (slot ps) into registers HERE
            keep_slot(kS[ps], qS[ps], eS[ps], wvS[ps]);
        }
    }

    // peeled final outer iteration: t = 508..511, prefetch clamped
#pragma unroll
    for (int j = 0; j < 4; ++j) {
        const int ps = (j + 2) & 3;
        int tp = 510 + j;
        if (tp > T_STEPS - 1) tp = T_STEPS - 1;
        const float* p = pb + (size_t)tp * STRIDE;
        kS[ps]  = *(const f32x4*)(p + col0);
        qS[ps]  = *(const f32x4*)(p + 2 * NDIM + col0);
        eS[ps]  = p[3 * NDIM + row];
        wvS[ps] = p[NDIM + row];

        float dot = 0.0f;
#pragma unroll
        for (int u = 0; u < 4; ++u) {
            float t0  = fmaf(-eS[j], S[u], wvS[j]);
            float pre = fmaf(kS[j][u], t0, S[u]);
            S[u] = tanh_fast(pre);
            dot = fmaf(S[u], qS[j][u], dot);
        }
        dot = dpp_reduce32(dot);

        if ((threadIdx.x & 31) == 31)
            *opc = dot;
        opc += BATCH * NDIM;
    }

    *(f32x4*)(out + (size_t)T_STEPS * BATCH * NDIM
              + ((size_t)b * NDIM + row) * NDIM + col0) = S;
}

// ---------------- silu epilogue: y = d^2 * sigmoid(d) over out[0:OUT_N] ----
__global__ __launch_bounds__(256) void silu_kernel(float* __restrict__ out)
{
    const int i = blockIdx.x * 256 + threadIdx.x;  // f32x4 index
    f32x4 d = ((const f32x4*)out)[i];
    f32x4 y;
#pragma unroll
    for (int j = 0; j < 4; ++j) {
        float sg = __builtin_amdgcn_rcpf(
            1.0f + __builtin_amdgcn_exp2f(-d[j] * 1.4426950408889634f));
        y[j] = d[j] * d[j] * sg;
    }
    ((f32x4*)out)[i] = y;
}

extern "C" void kernel_launch(void* const* d_in, const int* in_sizes, int n_in,
                              void* d_out, int out_size, void* d_ws, size_t ws_size,
                              hipStream_t stream) {
    const float* x  = (const float*)d_in[0];
    const float* S0 = (const float*)d_in[1];
    const float* wk = (const float*)d_in[2];
    const float* wv = (const float*)d_in[3];
    const float* wq = (const float*)d_in[4];
    const float* we = (const float*)d_in[5];
    const float* ww = (const float*)d_in[6];
    float* out = (float*)d_out;
    float* C   = (float*)d_ws;
    unsigned short* W2 = (unsigned short*)((char*)d_ws + C_BYTES);

    wconv_kernel<<<640, 256, 0, stream>>>(wk, wv, wq, we, ww, W2);
    gemm5_kernel<<<256, 512, 0, stream>>>(x, W2, C);
    knorm_kernel<<<MROWS / 4, 256, 0, stream>>>(C);
    ntm_scan_kernel<<<512, 256, 0, stream>>>(C, S0, out);
    silu_kernel<<<OUT_N / 1024, 256, 0, stream>>>(out);
}

// Round 8
// 268.135 us; speedup vs baseline: 1.3267x; 1.3267x over previous
//
#include <hip/hip_runtime.h>
#include <hip/hip_bf16.h>

// NTM cell forward: T=512, B=32, D=1024, N=128. All I/O f32.
// R17: measurement round. R16's keep-alive pin FALSIFIED the load-sinking
// theory (scan 128->222us, VALUBusy 73->43%, VGPR still 32): R14's scan
// was already correctly pipelined (VGPR=32 == 2 slots in flight + S).
// Scan reverted to R14 verbatim, but SPLIT into two dispatches
// (t 0..255 -> S_mid checkpoint in ws -> t 256..511) so each scan
// dispatch is ~65us and gemm5 (~120us, never yet profiled -- top-5 was
// always flooded by 128us scan rows) finally surfaces in the PMC table.
// gemm5 byte-identical to R14 (the specimen under measurement).
// ws: C (41,943,040) | W2 (1,310,720) | S_mid (8,388,608).

typedef __attribute__((ext_vector_type(8))) short bf16x8;
typedef __attribute__((ext_vector_type(4))) float f32x4;
typedef __attribute__((ext_vector_type(2))) float f32x2;
typedef __attribute__((ext_vector_type(4))) unsigned short u16x4;
typedef __attribute__((ext_vector_type(8))) unsigned short u16x8;

static constexpr int T_STEPS = 512;
static constexpr int BATCH   = 32;
static constexpr int DDIM    = 1024;
static constexpr int NDIM    = 128;
static constexpr int LDC     = 5 * NDIM;         // 640
static constexpr int MROWS   = T_STEPS * BATCH;  // 16384
static constexpr int OUT_N   = T_STEPS * BATCH * NDIM;  // 2,097,152

static constexpr size_t C_BYTES  = (size_t)MROWS * LDC * 4;   // 41,943,040
static constexpr size_t W2_BYTES = 5ull * NDIM * DDIM * 2;    // 1,310,720

// round-to-nearest-even f32 -> bf16
__device__ __forceinline__ unsigned short rne_bf16(float v) {
    unsigned u = __builtin_bit_cast(unsigned, v);
    u += 0x7FFFu + ((u >> 16) & 1u);
    return (unsigned short)(u >> 16);
}

// ---------------- Phase 0: W f32 -> frag-swizzled bf16 ----------------
__global__ __launch_bounds__(256) void wconv_kernel(
    const float* __restrict__ w0, const float* __restrict__ w1,
    const float* __restrict__ w2, const float* __restrict__ w3,
    const float* __restrict__ w4,
    unsigned short* __restrict__ W2)
{
    const int idx = blockIdx.x * 256 + threadIdx.x;   // f32x4 index, 163840 total
    const size_t e = (size_t)idx * 4;
    const int bn = (int)(e >> 17);                    // 131,072 elems per weight
    const int r  = (int)(e & 131071);
    const int n  = r >> 10;
    const int k  = r & 1023;

    const float* wp = w0;
    if (bn == 1) wp = w1;
    else if (bn == 2) wp = w2;
    else if (bn == 3) wp = w3;
    else if (bn == 4) wp = w4;

    f32x4 v = *(const f32x4*)(wp + r);
    u16x4 h;
#pragma unroll
    for (int j = 0; j < 4; ++j) h[j] = rne_bf16(v[j]);

    const int kk   = k >> 5;
    const int quad = (k >> 3) & 3;
    const size_t off = ((((size_t)(bn * 32 + kk) * 128 + n) * 4 + quad) * 8) + (k & 7);
    *(u16x4*)(W2 + off) = h;
}

// ---------------- Phase 1: A-resident GEMM, bn-pass structure ----------------
template<int BN0, int NB>
__device__ __forceinline__ void gemm_pass(
    const unsigned short (&lds)[64 * 1024],
    const unsigned short* __restrict__ bp,
    float* __restrict__ C,
    int m0, int wave, int quad, int l16, int aswz)
{
    auto LDA = [&](int mi, int kk) -> bf16x8 {
        const int byteo = (mi * 16 + l16) * 2048 + ((kk * 64 + quad * 16) ^ aswz);
        return *(const bf16x8*)((const char*)lds + byteo);
    };

    f32x4 acc[NB][4];
#pragma unroll
    for (int q = 0; q < NB; ++q)
#pragma unroll
        for (int mi = 0; mi < 4; ++mi) acc[q][mi] = (f32x4)(0.0f);

    const unsigned short* bpp[NB];
#pragma unroll
    for (int q = 0; q < NB; ++q) bpp[q] = bp + (size_t)(BN0 + q) * 131072;

    bf16x8 aC[4], bC[NB], aN[4], bN[NB];
#pragma unroll
    for (int mi = 0; mi < 4; ++mi) aC[mi] = LDA(mi, 0);
#pragma unroll
    for (int q = 0; q < NB; ++q) bC[q] = *(const bf16x8*)bpp[q];

    for (int kk = 0; kk < 32; kk += 2) {
        // prefetch kk+1
#pragma unroll
        for (int mi = 0; mi < 4; ++mi) aN[mi] = LDA(mi, kk + 1);
#pragma unroll
        for (int q = 0; q < NB; ++q)
            bN[q] = *(const bf16x8*)(bpp[q] + (size_t)(kk + 1) * 4096);
        // compute kk
#pragma unroll
        for (int q = 0; q < NB; ++q)
#pragma unroll
            for (int mi = 0; mi < 4; ++mi)
                acc[q][mi] = __builtin_amdgcn_mfma_f32_16x16x32_bf16(
                    aC[mi], bC[q], acc[q][mi], 0, 0, 0);
        // prefetch kk+2
        if (kk < 30) {
#pragma unroll
            for (int mi = 0; mi < 4; ++mi) aC[mi] = LDA(mi, kk + 2);
#pragma unroll
            for (int q = 0; q < NB; ++q)
                bC[q] = *(const bf16x8*)(bpp[q] + (size_t)(kk + 2) * 4096);
        }
        // compute kk+1
#pragma unroll
        for (int q = 0; q < NB; ++q)
#pragma unroll
            for (int mi = 0; mi < 4; ++mi)
                acc[q][mi] = __builtin_amdgcn_mfma_f32_16x16x32_bf16(
                    aN[mi], bN[q], acc[q][mi], 0, 0, 0);
    }

    // per-pass epilogue (overlaps next pass's loads)
#pragma unroll
    for (int q = 0; q < NB; ++q)
#pragma unroll
        for (int mi = 0; mi < 4; ++mi) {
            const int rw = m0 + mi * 16 + quad * 4;
            const int cl = (BN0 + q) * 128 + wave * 16 + l16;
#pragma unroll
            for (int r = 0; r < 4; ++r)
                C[(size_t)(rw + r) * LDC + cl] = acc[q][mi][r];
        }
}

// 256 blocks, 512 threads (8 waves), 1 block/CU (128 KiB LDS).
__global__ __launch_bounds__(512, 2) void gemm5_kernel(
    const float* __restrict__ x,
    const unsigned short* __restrict__ W2,
    float* __restrict__ C)
{
    __shared__ unsigned short lds[64 * 1024];  // 131,072 B

    const int m0   = blockIdx.x * 64;
    const int tid  = threadIdx.x;
    const int wave = tid >> 6, lane = tid & 63;
    const int quad = lane >> 4, l16 = lane & 15;

    // ---- stage: coalesced 32 B/thread/iter, swizzled 16 B LDS writes ----
    {
        const int k8 = tid & 127;       // 8-elem k-group 0..127
        const int rb = tid >> 7;        // 0..3
#pragma unroll 4
        for (int it = 0; it < 16; ++it) {
            const int row = it * 4 + rb;
            const float* src = x + (size_t)(m0 + row) * DDIM + k8 * 8;
            f32x4 v0 = *(const f32x4*)src;
            f32x4 v1 = *(const f32x4*)(src + 4);
            u16x8 h;
            h[0] = rne_bf16(v0[0]); h[1] = rne_bf16(v0[1]);
            h[2] = rne_bf16(v0[2]); h[3] = rne_bf16(v0[3]);
            h[4] = rne_bf16(v1[0]); h[5] = rne_bf16(v1[1]);
            h[6] = rne_bf16(v1[2]); h[7] = rne_bf16(v1[3]);
            const int byteo = row * 2048 + ((k8 * 16) ^ ((row & 7) << 4));
            *(u16x8*)((char*)lds + byteo) = h;
        }
    }
    __syncthreads();

    const int aswz = (l16 & 7) << 4;
    const unsigned short* bp = W2 + ((size_t)((wave * 16 + l16) * 4 + quad)) * 8;

    gemm_pass<0, 2>(lds, bp, C, m0, wave, quad, l16, aswz);
    gemm_pass<2, 2>(lds, bp, C, m0, wave, quad, l16, aswz);
    gemm_pass<4, 1>(lds, bp, C, m0, wave, quad, l16, aswz);
}

// ---------------- knorm prep ----------------
__global__ __launch_bounds__(256) void knorm_kernel(float* __restrict__ C)
{
    const int r    = blockIdx.x * 4 + (threadIdx.x >> 6);
    const int lane = threadIdx.x & 63;
    float* base = C + (size_t)r * LDC;

    f32x2 k2 = *(const f32x2*)(base + lane * 2);
    f32x2 v2 = *(const f32x2*)(base + NDIM + lane * 2);
    f32x2 w2 = *(const f32x2*)(base + 4 * NDIM + lane * 2);

    float ss = k2.x * k2.x + k2.y * k2.y;
#pragma unroll
    for (int off = 32; off >= 1; off >>= 1) ss += __shfl_xor(ss, off, 64);
    float inv = __builtin_amdgcn_rcpf(sqrtf(ss) + 1e-6f);

    f32x2 kn = {k2.x * inv, k2.y * inv};
    f32x2 wv = {v2.x * w2.x, v2.y * w2.y};
    *(f32x2*)(base + lane * 2) = kn;
    *(f32x2*)(base + NDIM + lane * 2) = wv;
}

// ---------------- recurrent scan ----------------
__device__ __forceinline__ float tanh_fast(float xx) {
    float ex = __builtin_amdgcn_exp2f(xx * 2.8853900817779268f);  // e^(2x)
    float r  = __builtin_amdgcn_rcpf(ex + 1.0f);
    return fmaf(-2.0f, r, 1.0f);
}

template <int CTRL, int RMASK>
__device__ __forceinline__ float dpp_add(float x) {
    int yi = __builtin_amdgcn_update_dpp(
        0, __builtin_bit_cast(int, x), CTRL, RMASK, 0xF, true);
    return x + __builtin_bit_cast(float, yi);
}

// Sum across each 32-lane group; valid in lanes 16..31 / 48..63.
__device__ __forceinline__ float dpp_reduce32(float x) {
    x = dpp_add<0xB1,  0xF>(x);  // + lane^1
    x = dpp_add<0x4E,  0xF>(x);  // + lane^2
    x = dpp_add<0x141, 0xF>(x);  // row_half_mirror: + lane^4
    x = dpp_add<0x140, 0xF>(x);  // row_mirror: + lane^8
    x = dpp_add<0x142, 0xA>(x);  // row_bcast15: rows 1,3 += row 0,2 sum
    return x;
}

// Half-sequence scan: NOUTER unrolled-4 outer iterations starting at t0,
// reading S from Sin and writing the final S to Sout. TAIL adds the
// clamped peeled iteration (last 4 timesteps of the whole sequence).
// Body identical to R14 (128us total, VALUBusy 73%).
template<int NOUTER, bool TAIL>
__global__ __launch_bounds__(256, 2) void ntm_scan_part(
    const float* __restrict__ C, const float* __restrict__ Sin,
    float* __restrict__ Sout, float* __restrict__ out, int t0)
{
    const int L    = blockIdx.x;            // 0..511
    const int b    = (L & 7) + 8 * ((L >> 3) & 3);
    const int row  = (L >> 5) * 8 + (threadIdx.x >> 5);
    const int g    = threadIdx.x & 31;
    const int col0 = g * 4;

    f32x4 S = *(const f32x4*)(Sin + ((size_t)b * NDIM + row) * NDIM + col0);

    const size_t STRIDE = (size_t)BATCH * LDC;
    const float* pb = C + (size_t)b * LDC;
    const float* p0 = pb + (size_t)t0 * STRIDE;

    f32x4 kS[4], qS[4];
    float eS[4], wvS[4];

#pragma unroll
    for (int s = 0; s < 2; ++s) {
        const float* p = p0 + (size_t)s * STRIDE;
        kS[s]  = *(const f32x4*)(p + col0);
        qS[s]  = *(const f32x4*)(p + 2 * NDIM + col0);
        eS[s]  = p[3 * NDIM + row];
        wvS[s] = p[NDIM + row];
    }

    float* opc = out + (size_t)t0 * BATCH * NDIM + (size_t)b * NDIM + row;
    const float* pc = p0 + 2 * STRIDE;           // prefetch cursor (t+2)

    for (int ti = 0; ti < NOUTER; ++ti) {
#pragma unroll
        for (int j = 0; j < 4; ++j) {
            const int ps = (j + 2) & 3;
            kS[ps]  = *(const f32x4*)(pc + col0);
            qS[ps]  = *(const f32x4*)(pc + 2 * NDIM + col0);
            eS[ps]  = pc[3 * NDIM + row];
            wvS[ps] = pc[NDIM + row];
            pc += STRIDE;

            float dot = 0.0f;
#pragma unroll
            for (int u = 0; u < 4; ++u) {
                float t0v = fmaf(-eS[j], S[u], wvS[j]);
                float pre = fmaf(kS[j][u], t0v, S[u]);
                S[u] = tanh_fast(pre);
                dot = fmaf(S[u], qS[j][u], dot);
            }
            dot = dpp_reduce32(dot);

            if ((threadIdx.x & 31) == 31)
                *opc = dot;  // raw; silu in epilogue
            opc += BATCH * NDIM;
        }
    }

    if (TAIL) {
        // peeled final outer iteration, prefetch clamped to T-1
#pragma unroll
        for (int j = 0; j < 4; ++j) {
            const int ps = (j + 2) & 3;
            int tp = t0 + NOUTER * 4 + 2 + j;
            if (tp > T_STEPS - 1) tp = T_STEPS - 1;
            const float* p = pb + (size_t)tp * STRIDE;
            kS[ps]  = *(const f32x4*)(p + col0);
            qS[ps]  = *(const f32x4*)(p + 2 * NDIM + col0);
            eS[ps]  = p[3 * NDIM + row];
            wvS[ps] = p[NDIM + row];

            float dot = 0.0f;
#pragma unroll
            for (int u = 0; u < 4; ++u) {
                float t0v = fmaf(-eS[j], S[u], wvS[j]);
                float pre = fmaf(kS[j][u], t0v, S[u]);
                S[u] = tanh_fast(pre);
                dot = fmaf(S[u], qS[j][u], dot);
            }
            dot = dpp_reduce32(dot);

            if ((threadIdx.x & 31) == 31)
                *opc = dot;
            opc += BATCH * NDIM;
        }
    }

    *(f32x4*)(Sout + ((size_t)b * NDIM + row) * NDIM + col0) = S;
}

// ---------------- silu epilogue: y = d^2 * sigmoid(d) over out[0:OUT_N] ----
__global__ __launch_bounds__(256) void silu_kernel(float* __restrict__ out)
{
    const int i = blockIdx.x * 256 + threadIdx.x;  // f32x4 index
    f32x4 d = ((const f32x4*)out)[i];
    f32x4 y;
#pragma unroll
    for (int j = 0; j < 4; ++j) {
        float sg = __builtin_amdgcn_rcpf(
            1.0f + __builtin_amdgcn_exp2f(-d[j] * 1.4426950408889634f));
        y[j] = d[j] * d[j] * sg;
    }
    ((f32x4*)out)[i] = y;
}

extern "C" void kernel_launch(void* const* d_in, const int* in_sizes, int n_in,
                              void* d_out, int out_size, void* d_ws, size_t ws_size,
                              hipStream_t stream) {
    const float* x  = (const float*)d_in[0];
    const float* S0 = (const float*)d_in[1];
    const float* wk = (const float*)d_in[2];
    const float* wv = (const float*)d_in[3];
    const float* wq = (const float*)d_in[4];
    const float* we = (const float*)d_in[5];
    const float* ww = (const float*)d_in[6];
    float* out = (float*)d_out;
    float* C   = (float*)d_ws;
    unsigned short* W2 = (unsigned short*)((char*)d_ws + C_BYTES);
    float* S_mid = (float*)((char*)d_ws + C_BYTES + W2_BYTES);

    wconv_kernel<<<640, 256, 0, stream>>>(wk, wv, wq, we, ww, W2);
    gemm5_kernel<<<256, 512, 0, stream>>>(x, W2, C);
    knorm_kernel<<<MROWS / 4, 256, 0, stream>>>(C);
    // t 0..255 (prefetch reaches t=257, valid), S0 -> S_mid
    ntm_scan_part<64, false><<<512, 256, 0, stream>>>(C, S0, S_mid, out, 0);
    // t 256..507 main + 508..511 clamped tail, S_mid -> final S in out
    ntm_scan_part<63, true><<<512, 256, 0, stream>>>(
        C, S_mid, out + (size_t)OUT_N, out, 256);
    silu_kernel<<<OUT_N / 1024, 256, 0, stream>>>(out);
}